// Round 4
// baseline (191.427 us; speedup 1.0000x reference)
//
#include <hip/hip_runtime.h>
#include <stdint.h>

// Problem: x[B=32][N=8192][D=64] fp32 -> out[B][D][D][D] fp32 (centered 3rd moment)
#define B_SZ 32
#define N_SZ 8192
#define D_SZ 64

typedef _Float16 half8 __attribute__((ext_vector_type(8)));
typedef float f32x4 __attribute__((ext_vector_type(4)));

#define AS1 __attribute__((address_space(1)))
#define AS3 __attribute__((address_space(3)))

#define MFMA16(Aop, Bop, Cop) __builtin_amdgcn_mfma_f32_16x16x32_f16(Aop, Bop, Cop, 0, 0, 0)

// Layout v2 (per 4096-half granule of 64 n): chunk (d, cc) [8 halves, n=cc*8..+8]
// lives at 16B-slot:  slot(d,cc) = (d&3)*128 + (d>>2)*8 + (cc ^ (((d>>2)&1)<<2))
// -> transpose stores are lane-contiguous; GEMM reads are bank-uniform (8 lanes
//    per 4-bank group per ds_read_b128, same class as the v1 swizzle: 0 conflicts).

// ---------------------------------------------------------------------------
// Kernel 1: per-batch column sums. grid = 32 b * 32 slabs (256 n-rows each).
// ---------------------------------------------------------------------------
__global__ __launch_bounds__(256) void tp_mean_kernel(const float* __restrict__ x,
                                                      float* __restrict__ sums) {
    const int b    = blockIdx.x >> 5;
    const int slab = blockIdx.x & 31;
    const int d4   = threadIdx.x & 15;
    const int nr   = threadIdx.x >> 4;
    const float* base = x + (size_t)b * (N_SZ * D_SZ) + (size_t)(slab * 256 + nr) * D_SZ + d4 * 4;
    f32x4 s = {0.f, 0.f, 0.f, 0.f};
#pragma unroll
    for (int i = 0; i < 16; i++)
        s += *(const f32x4*)(base + i * 16 * D_SZ);
    __shared__ f32x4 red[16][16];
    red[nr][d4] = s;
    __syncthreads();
    if (threadIdx.x < 16) {
        f32x4 tot = red[0][threadIdx.x];
#pragma unroll
        for (int j = 1; j < 16; j++) tot += red[j][threadIdx.x];
        atomicAdd(&sums[b * 64 + threadIdx.x * 4 + 0], tot[0]);
        atomicAdd(&sums[b * 64 + threadIdx.x * 4 + 1], tot[1]);
        atomicAdd(&sums[b * 64 + threadIdx.x * 4 + 2], tot[2]);
        atomicAdd(&sums[b * 64 + threadIdx.x * 4 + 3], tot[3]);
    }
}

// ---------------------------------------------------------------------------
// Kernel 2: center, cast fp16, register transpose into layout v2.
// Within-granule thread t' (0..127): D = t'>>3 (d-quad), cc' = t'&7,
// cc = cc' ^ ((D&1)<<2).  Thread reads 8 f32x4 (n = cc*8..+8, d = 4D..+3),
// writes 4 half8 at slot c*128 + t'  -> 1KB-contiguous per wave per c.
// ---------------------------------------------------------------------------
__global__ __launch_bounds__(256) void tp_transpose_kernel(const float* __restrict__ x,
                                                           const float* __restrict__ sums,
                                                           _Float16* __restrict__ xcS) {
    const int b    = blockIdx.x >> 6;
    const int tp   = blockIdx.x & 63;
    const int t    = threadIdx.x;
    const int tile = tp * 2 + (t >> 7);
    const int tpr  = t & 127;            // t'
    const int D    = tpr >> 3;           // d-quad 0..15
    const int ccp  = tpr & 7;            // cc'
    const int cc   = ccp ^ ((D & 1) << 2);

    f32x4 mean4 = *(const f32x4*)(sums + b * 64 + D * 4) * (1.0f / (float)N_SZ);
    const float* src = x + (size_t)b * (N_SZ * D_SZ) + (size_t)(tile * 64 + cc * 8) * D_SZ + D * 4;
    f32x4 v[8];
#pragma unroll
    for (int i = 0; i < 8; i++)
        v[i] = *(const f32x4*)(src + i * D_SZ);

    _Float16* dstb = xcS + (size_t)b * (N_SZ * D_SZ) + (size_t)tile * 4096;
#pragma unroll
    for (int c = 0; c < 4; c++) {
        half8 o;
#pragma unroll
        for (int i = 0; i < 8; i++)
            o[i] = (_Float16)(v[i][c] - mean4[c]);
        *(half8*)(dstb + (c * 128 + tpr) * 8) = o;
    }
}

// ---------------------------------------------------------------------------
// Kernel 3: symmetric batched GEMM, 16x16x32 MFMA, single-barrier double-
// buffered pipeline. grid = (16 e-quads, 32 b). wg = 4 waves = (p, h).
// Mega-iter T stages 128 n (2 granules per h-tile) into buf[(T+1)&1] right
// after the barrier, then computes from buf[T&1] -> vmcnt drain at the next
// barrier waits on loads that are ~2500 cyc old (latency covered).
// ---------------------------------------------------------------------------
__global__ __launch_bounds__(256, 2) void tp_gemm_kernel(const _Float16* __restrict__ xcS,
                                                         float* __restrict__ out) {
    const int eg   = blockIdx.x;          // 0..15
    const int b    = blockIdx.y;          // 0..31
    const int tid  = threadIdx.x;
    const int lane = tid & 63;
    const int wv   = tid >> 6;            // 0..3
    const int h    = wv & 1;              // N-half
    const int p    = wv >> 1;             // e-pair within quad
    const int q    = lane >> 4;           // 0..3
    const int m    = lane & 15;
    const int e0   = eg * 4 + p * 2;

    __shared__ __align__(16) char ldsraw[65536];   // 2 bufs x 2 h x 2 granules x 8KB
    float* redL = (float*)ldsraw;                  // aliased for reduction (40KB)

    // staging source: wave (p,h) loads the p-half of each granule of tile h
    const _Float16* gbase = xcS + (size_t)b * (N_SZ * D_SZ)
                          + (size_t)h * (N_SZ / 2) * D_SZ
                          + (size_t)(p * 2048 + lane * 8);

    // fragment byte offsets within a granule (layout v2):
    // slot(r,c) = (r&3)*128 + (r>>2)*8 + (c ^ (((r>>2)&1)<<2)); byte = slot*16
    int aOff[2][4], sOff[2][2];
#pragma unroll
    for (int ks = 0; ks < 2; ks++) {
        const int c = ks * 4 + q;
#pragma unroll
        for (int i = 0; i < 4; i++) {
            const int r = i * 16 + m;
            const int rq = r >> 2;
            aOff[ks][i] = ((r & 3) * 128 + rq * 8 + (c ^ ((rq & 1) << 2))) * 16;
        }
#pragma unroll
        for (int j = 0; j < 2; j++) {
            const int e = e0 + j;
            const int eq = e >> 2;
            sOff[ks][j] = ((e & 3) * 128 + eq * 8 + (c ^ ((eq & 1) << 2))) * 16;
        }
    }

    f32x4 acc[2][10];
#pragma unroll
    for (int ej = 0; ej < 2; ej++)
#pragma unroll
        for (int k = 0; k < 10; k++)
            acc[ej][k] = (f32x4){0.f, 0.f, 0.f, 0.f};

    // stage mega-tile T into buffer bi: 2 granules (8KB each) of my h-tile
    auto stage = [&](int T, int bi) {
        _Float16* lb = (_Float16*)(ldsraw + bi * 32768 + h * 16384 + p * 4096);
        const _Float16* gb = gbase + (size_t)T * 8192;
#pragma unroll
        for (int g = 0; g < 2; g++)
#pragma unroll
            for (int k = 0; k < 4; k++)
                __builtin_amdgcn_global_load_lds(
                    (const AS1 void*)(gb + g * 4096 + k * 512),
                    (AS3 void*)(lb + g * 4096 + k * 512), 16, 0, 0);
    };

    stage(0, 0);

    for (int T = 0; T < 32; T++) {
        __syncthreads();                  // drains loads for buf[T&1]
        if (T < 31) stage(T + 1, (T + 1) & 1);
        const char* hb = ldsraw + (T & 1) * 32768 + h * 16384;
#pragma unroll
        for (int g = 0; g < 2; g++) {
            const char* tb = hb + g * 8192;
#pragma unroll
            for (int ks = 0; ks < 2; ks++) {
                half8 A0 = *(const half8*)(tb + aOff[ks][0]);
                half8 A1 = *(const half8*)(tb + aOff[ks][1]);
                half8 A2 = *(const half8*)(tb + aOff[ks][2]);
                half8 A3 = *(const half8*)(tb + aOff[ks][3]);
                half8 S0 = *(const half8*)(tb + sOff[ks][0]);
                half8 S1 = *(const half8*)(tb + sOff[ks][1]);
#pragma unroll
                for (int ej = 0; ej < 2; ej++) {
                    half8 S = ej ? S1 : S0;
                    half8 P0 = A0 * S;
                    half8 P1 = A1 * S;
                    half8 P2 = A2 * S;
                    half8 P3 = A3 * S;
                    acc[ej][0] = MFMA16(P0, A0, acc[ej][0]);
                    acc[ej][1] = MFMA16(P0, A1, acc[ej][1]);
                    acc[ej][2] = MFMA16(P0, A2, acc[ej][2]);
                    acc[ej][3] = MFMA16(P0, A3, acc[ej][3]);
                    acc[ej][4] = MFMA16(P1, A1, acc[ej][4]);
                    acc[ej][5] = MFMA16(P1, A2, acc[ej][5]);
                    acc[ej][6] = MFMA16(P1, A3, acc[ej][6]);
                    acc[ej][7] = MFMA16(P2, A2, acc[ej][7]);
                    acc[ej][8] = MFMA16(P2, A3, acc[ej][8]);
                    acc[ej][9] = MFMA16(P3, A3, acc[ej][9]);
                }
            }
        }
    }
    __syncthreads();                      // before LDS alias reuse

    // cross-h reduction: h==1 waves dump 20 f32x4/lane; h==0 waves add.
    if (h == 1) {
        float* w = redL + p * 5120 + lane * 4;
#pragma unroll
        for (int ej = 0; ej < 2; ej++)
#pragma unroll
            for (int k = 0; k < 10; k++)
                *(f32x4*)(w + (ej * 10 + k) * 256) = acc[ej][k];
    }
    __syncthreads();
    if (h == 0) {
        const float* rr = redL + p * 5120 + lane * 4;
#pragma unroll
        for (int ej = 0; ej < 2; ej++)
#pragma unroll
            for (int k = 0; k < 10; k++) {
                f32x4 w = *(const f32x4*)(rr + (ej * 10 + k) * 256);
                acc[ej][k] += w;
            }
        const float invn = 1.0f / (float)N_SZ;
        float* outb = out + (size_t)b * (D_SZ * D_SZ * D_SZ);
        // C/D layout (verified): col = lane&15 = f-within-block, row = q*4+reg
#pragma unroll
        for (int ej = 0; ej < 2; ej++) {
            const int e = e0 + ej;
            int idx = 0;
#pragma unroll
            for (int i = 0; i < 4; i++) {
#pragma unroll
                for (int j = i; j < 4; j++, idx++) {
                    f32x4 vsc = acc[ej][idx] * invn;
#pragma unroll
                    for (int r = 0; r < 4; r++)
                        outb[(size_t)(16 * i + q * 4 + r) * 4096 + e * 64 + 16 * j + m] = vsc[r];
                    if (i != j) {
                        *(f32x4*)&outb[(size_t)(16 * j + m) * 4096 + e * 64 + 16 * i + q * 4] = vsc;
                    }
                }
            }
        }
    }
}

// ---------------------------------------------------------------------------
extern "C" void kernel_launch(void* const* d_in, const int* in_sizes, int n_in,
                              void* d_out, int out_size, void* d_ws, size_t ws_size,
                              hipStream_t stream) {
    const float* x = (const float*)d_in[0];
    float* out = (float*)d_out;

    float* sums = (float*)d_ws;                           // 8 KB
    _Float16* xcS = (_Float16*)((char*)d_ws + 8192);      // 33.5 MB fp16

    hipMemsetAsync(sums, 0, B_SZ * D_SZ * sizeof(float), stream);
    tp_mean_kernel<<<dim3(B_SZ * 32), 256, 0, stream>>>(x, sums);
    tp_transpose_kernel<<<dim3(B_SZ * 64), 256, 0, stream>>>(x, sums, xcS);
    tp_gemm_kernel<<<dim3(16, B_SZ), 256, 0, stream>>>(xcS, out);
}